// Round 2
// baseline (147.547 us; speedup 1.0000x reference)
//
#include <hip/hip_runtime.h>
#include <hip/hip_bf16.h>
#include <cstddef>

// LSTMCell fused: z = [u|h] @ [W|U]^T + bW + bE ; gates ; c/h update.
// Device dtypes: fp32 in / fp32 out (evidence: in_npz 101MB ~= fp32 size;
// bf16 interp gave NaN). Internal compute: bf16 MFMA, fp32 accum (threshold
// 9.75e-2 allows bf16 precision).
// GEMM view: M=16384, N=2048 (4 gates x 512), K=1024.
// Tile: BM=128 x BH=32 h-cols x 4 gates, BK=64, 256 thr (4 waves).
// Staging: reg-stage fp32 -> cvt bf16 -> ds_write_b128 (global_load_lds can't
// convert dtype). Prefetch next tile's loads under current tile's MFMAs.

#define BDIM 16384
#define HDIM 512

typedef __attribute__((ext_vector_type(8))) short bf16x8;
typedef __attribute__((ext_vector_type(4))) float f32x4;

struct Params {
  const float* u;
  const float* h;
  const float* c;
  const float* W[4];   // Wi Wf Wg Wo  [512,512]
  const float* U[4];   // Ui Uf Ug Uo  [512,512]
  const float* bW[4];  // [512]
  const float* bE[4];  // [512]
  float* outh;
  float* outc;
};

__device__ __forceinline__ float sigmoidf_(float x) {
  return 1.0f / (1.0f + __expf(-x));
}

__device__ __forceinline__ bf16x8 cvt8(f32x4 a, f32x4 b) {
  bf16x8 r;
#pragma unroll
  for (int j = 0; j < 4; ++j) {
    __hip_bfloat16 t = __float2bfloat16(a[j]);
    r[j] = *reinterpret_cast<short*>(&t);
  }
#pragma unroll
  for (int j = 0; j < 4; ++j) {
    __hip_bfloat16 t = __float2bfloat16(b[j]);
    r[4 + j] = *reinterpret_cast<short*>(&t);
  }
  return r;
}

__launch_bounds__(256, 2)
__global__ void lstm_cell_kernel(Params p) {
  // LDS: A bf16 [128][64] (16 KB) + W bf16 [4][32][64] (16 KB)
  __shared__ char smem[32768];
  __shared__ float biasLDS[4][32];

  const int tid = threadIdx.x;
  const int w   = tid >> 6;
  const int l   = tid & 63;
  const int m_tile = blockIdx.x & 127;
  const int h_tile = blockIdx.x >> 7;

  char* smemA = smem;          // row stride 128 B
  char* smemW = smem + 16384;  // gate g at rows [g*32, g*32+32)

  const int rowA0 = m_tile * 128;
  const int nrow0 = h_tile * 32;

  if (tid < 128) {
    const int g = tid >> 5, hh = tid & 31;
    const int hc = nrow0 + hh;
    biasLDS[g][hh] = p.bW[g][hc] + p.bE[g][hc];
  }

  const int sr = tid >> 3;  // 0..31: row within each 32-row chunk
  const int sc = tid & 7;   // 0..7:  8-float group within 64-k row

  f32x4 acc[4][2][2] = {};  // [gate][mi][ni]
  f32x4 rg[16];             // staging regs: 8 chunks x 2 float4 (static idx)

  auto load_tile = [&](int kt) {
    const float* sA = (kt < 8) ? p.u : p.h;
    const int kc = (kt & 7) * 64;
#pragma unroll
    for (int cc = 0; cc < 4; ++cc) {
      const float* gp = sA + (size_t)(rowA0 + cc * 32 + sr) * 512 + kc + sc * 8;
      rg[cc * 2]     = *(const f32x4*)gp;
      rg[cc * 2 + 1] = *(const f32x4*)(gp + 4);
    }
#pragma unroll
    for (int cc = 0; cc < 4; ++cc) {
      const float* sW = (kt < 8) ? p.W[cc] : p.U[cc];
      const float* gp = sW + (size_t)(nrow0 + sr) * 512 + kc + sc * 8;
      rg[8 + cc * 2]     = *(const f32x4*)gp;
      rg[8 + cc * 2 + 1] = *(const f32x4*)(gp + 4);
    }
  };

  auto write_tile = [&]() {
#pragma unroll
    for (int cc = 0; cc < 4; ++cc)
      *(bf16x8*)(smemA + (cc * 32 + sr) * 128 + sc * 16) =
          cvt8(rg[cc * 2], rg[cc * 2 + 1]);
#pragma unroll
    for (int cc = 0; cc < 4; ++cc)
      *(bf16x8*)(smemW + (cc * 32 + sr) * 128 + sc * 16) =
          cvt8(rg[8 + cc * 2], rg[8 + cc * 2 + 1]);
  };

  auto compute = [&]() {
#pragma unroll
    for (int kk = 0; kk < 2; ++kk) {
      const int kb = kk * 64 + (l >> 4) * 16;
      bf16x8 a0 = *(const bf16x8*)(smemA + (w * 32 +      (l & 15)) * 128 + kb);
      bf16x8 a1 = *(const bf16x8*)(smemA + (w * 32 + 16 + (l & 15)) * 128 + kb);
#pragma unroll
      for (int g = 0; g < 4; ++g) {
#pragma unroll
        for (int ni = 0; ni < 2; ++ni) {
          bf16x8 b = *(const bf16x8*)(smemW + (g * 32 + ni * 16 + (l & 15)) * 128 + kb);
          acc[g][0][ni] = __builtin_amdgcn_mfma_f32_16x16x32_bf16(a0, b, acc[g][0][ni], 0, 0, 0);
          acc[g][1][ni] = __builtin_amdgcn_mfma_f32_16x16x32_bf16(a1, b, acc[g][1][ni], 0, 0, 0);
        }
      }
    }
  };

  load_tile(0);
  for (int kt = 0; kt < 16; ++kt) {
    write_tile();        // waits on in-flight global loads, cvt, ds_write
    __syncthreads();     // tiles visible
    if (kt < 15) load_tile(kt + 1);  // HBM latency hides under MFMAs
    compute();
    __syncthreads();     // reads done before next overwrite
  }

  // --- fused epilogue (fp32 c in, fp32 h/c out) ---
  // C/D layout: col = lane&15, row = (lane>>4)*4 + reg   [m89/m91]
  const int lr = (l >> 4) * 4;
  const int lc = l & 15;
#pragma unroll
  for (int mi = 0; mi < 2; ++mi) {
#pragma unroll
    for (int j = 0; j < 4; ++j) {
      const int row = rowA0 + w * 32 + mi * 16 + lr + j;
#pragma unroll
      for (int ni = 0; ni < 2; ++ni) {
        const int hc = nrow0 + ni * 16 + lc;
        const int bcol = ni * 16 + lc;
        const float zi = acc[0][mi][ni][j] + biasLDS[0][bcol];
        const float zf = acc[1][mi][ni][j] + biasLDS[1][bcol];
        const float zg = acc[2][mi][ni][j] + biasLDS[2][bcol];
        const float zo = acc[3][mi][ni][j] + biasLDS[3][bcol];
        const float ig = sigmoidf_(zi);
        const float fg = sigmoidf_(zf);
        const float gg = tanhf(zg);
        const float og = sigmoidf_(zo);
        const size_t idx = (size_t)row * 512 + hc;
        const float cv = p.c[idx];
        const float cn = fg * cv + ig * gg;
        const float hn = og * tanhf(cn);
        p.outh[idx] = hn;
        p.outc[idx] = cn;
      }
    }
  }
}

extern "C" void kernel_launch(void* const* d_in, const int* in_sizes, int n_in,
                              void* d_out, int out_size, void* d_ws, size_t ws_size,
                              hipStream_t stream) {
  Params p;
  p.u = (const float*)d_in[0];
  p.h = (const float*)d_in[1];
  p.c = (const float*)d_in[2];
  p.W[0] = (const float*)d_in[3];
  p.bW[0] = (const float*)d_in[4];
  p.W[1] = (const float*)d_in[5];
  p.bW[1] = (const float*)d_in[6];
  p.W[2] = (const float*)d_in[7];
  p.bW[2] = (const float*)d_in[8];
  p.W[3] = (const float*)d_in[9];
  p.bW[3] = (const float*)d_in[10];
  p.U[0] = (const float*)d_in[11];
  p.U[1] = (const float*)d_in[12];
  p.U[2] = (const float*)d_in[13];
  p.U[3] = (const float*)d_in[14];
  p.bE[0] = (const float*)d_in[15];
  p.bE[1] = (const float*)d_in[16];
  p.bE[2] = (const float*)d_in[17];
  p.bE[3] = (const float*)d_in[18];
  p.outh = (float*)d_out;
  p.outc = (float*)d_out + (size_t)BDIM * HDIM;

  dim3 grid(2048);
  dim3 block(256);
  hipLaunchKernelGGL(lstm_cell_kernel, grid, block, 0, stream, p);
}

// Round 3
// 136.883 us; speedup vs baseline: 1.0779x; 1.0779x over previous
//
#include <hip/hip_runtime.h>
#include <hip/hip_bf16.h>
#include <cstddef>

// LSTMCell fused: z = [u|h] @ [W|U]^T + bW + bE ; gates ; c/h update.
// fp32 in / fp32 out; bf16 MFMA internal, fp32 accum.
// GEMM view: M=16384, N=2048 (4 gates x 512), K=1024.
// Tile: BM=128 x BH=32 h-cols x 4 gates, BK=64, 256 thr (4 waves).
// R2: XOR-swizzle LDS columns (col ^= (row&7)<<4) — kills the 16-lane/slot
// ds_read_b128 bank conflict (row stride 128 B == 32 banks).

#define BDIM 16384
#define HDIM 512

typedef __attribute__((ext_vector_type(8))) short bf16x8;
typedef __attribute__((ext_vector_type(4))) float f32x4;

struct Params {
  const float* u;
  const float* h;
  const float* c;
  const float* W[4];   // Wi Wf Wg Wo  [512,512]
  const float* U[4];   // Ui Uf Ug Uo  [512,512]
  const float* bW[4];  // [512]
  const float* bE[4];  // [512]
  float* outh;
  float* outc;
};

__device__ __forceinline__ float sigmoidf_(float x) {
  return 1.0f / (1.0f + __expf(-x));
}

__device__ __forceinline__ bf16x8 cvt8(f32x4 a, f32x4 b) {
  bf16x8 r;
#pragma unroll
  for (int j = 0; j < 4; ++j) {
    __hip_bfloat16 t = __float2bfloat16(a[j]);
    r[j] = *reinterpret_cast<short*>(&t);
  }
#pragma unroll
  for (int j = 0; j < 4; ++j) {
    __hip_bfloat16 t = __float2bfloat16(b[j]);
    r[4 + j] = *reinterpret_cast<short*>(&t);
  }
  return r;
}

__launch_bounds__(256, 2)
__global__ void lstm_cell_kernel(Params p) {
  // LDS: A bf16 [128][64] (16 KB) + W bf16 [4][32][64] (16 KB), swizzled cols
  __shared__ char smem[32768];
  __shared__ float biasLDS[4][32];

  const int tid = threadIdx.x;
  const int w   = tid >> 6;
  const int l   = tid & 63;
  const int m_tile = blockIdx.x & 127;
  const int h_tile = blockIdx.x >> 7;

  char* smemA = smem;          // row stride 128 B
  char* smemW = smem + 16384;  // gate g at rows [g*32, g*32+32)

  const int rowA0 = m_tile * 128;
  const int nrow0 = h_tile * 32;

  if (tid < 128) {
    const int g = tid >> 5, hh = tid & 31;
    const int hc = nrow0 + hh;
    biasLDS[g][hh] = p.bW[g][hc] + p.bE[g][hc];
  }

  const int sr = tid >> 3;  // 0..31: row within each 32-row chunk
  const int sc = tid & 7;   // 0..7:  16B slot within 128B row
  const int wcol = (sc * 16) ^ ((sr & 7) << 4);  // swizzled write column

  f32x4 acc[4][2][2] = {};  // [gate][mi][ni]
  f32x4 rg[16];             // staging regs (static idx)

  auto load_tile = [&](int kt) {
    const float* sA = (kt < 8) ? p.u : p.h;
    const int kc = (kt & 7) * 64;
#pragma unroll
    for (int cc = 0; cc < 4; ++cc) {
      const float* gp = sA + (size_t)(rowA0 + cc * 32 + sr) * 512 + kc + sc * 8;
      rg[cc * 2]     = *(const f32x4*)gp;
      rg[cc * 2 + 1] = *(const f32x4*)(gp + 4);
    }
#pragma unroll
    for (int cc = 0; cc < 4; ++cc) {
      const float* sW = (kt < 8) ? p.W[cc] : p.U[cc];
      const float* gp = sW + (size_t)(nrow0 + sr) * 512 + kc + sc * 8;
      rg[8 + cc * 2]     = *(const f32x4*)gp;
      rg[8 + cc * 2 + 1] = *(const f32x4*)(gp + 4);
    }
  };

  auto write_tile = [&]() {
#pragma unroll
    for (int cc = 0; cc < 4; ++cc)
      *(bf16x8*)(smemA + (cc * 32 + sr) * 128 + wcol) =
          cvt8(rg[cc * 2], rg[cc * 2 + 1]);
#pragma unroll
    for (int cc = 0; cc < 4; ++cc)
      *(bf16x8*)(smemW + (cc * 32 + sr) * 128 + wcol) =
          cvt8(rg[8 + cc * 2], rg[8 + cc * 2 + 1]);
  };

  const int xr = (l & 7) << 4;  // per-lane swizzle term (row&7 == l&7 for all reads)

  auto compute = [&]() {
#pragma unroll
    for (int kk = 0; kk < 2; ++kk) {
      const int kb = (kk * 64 + (l >> 4) * 16) ^ xr;
      bf16x8 a0 = *(const bf16x8*)(smemA + (w * 32 +      (l & 15)) * 128 + kb);
      bf16x8 a1 = *(const bf16x8*)(smemA + (w * 32 + 16 + (l & 15)) * 128 + kb);
#pragma unroll
      for (int g = 0; g < 4; ++g) {
#pragma unroll
        for (int ni = 0; ni < 2; ++ni) {
          bf16x8 b = *(const bf16x8*)(smemW + (g * 32 + ni * 16 + (l & 15)) * 128 + kb);
          acc[g][0][ni] = __builtin_amdgcn_mfma_f32_16x16x32_bf16(a0, b, acc[g][0][ni], 0, 0, 0);
          acc[g][1][ni] = __builtin_amdgcn_mfma_f32_16x16x32_bf16(a1, b, acc[g][1][ni], 0, 0, 0);
        }
      }
    }
  };

  load_tile(0);
  for (int kt = 0; kt < 16; ++kt) {
    write_tile();        // waits on in-flight global loads, cvt, ds_write
    __syncthreads();     // tiles visible
    if (kt < 15) load_tile(kt + 1);  // HBM latency hides under MFMAs
    compute();
    __syncthreads();     // reads done before next overwrite
  }

  // --- fused epilogue (fp32 c in, fp32 h/c out) ---
  // C/D layout: col = lane&15, row = (lane>>4)*4 + reg   [m89/m91]
  const int lr = (l >> 4) * 4;
  const int lc = l & 15;
#pragma unroll
  for (int mi = 0; mi < 2; ++mi) {
#pragma unroll
    for (int j = 0; j < 4; ++j) {
      const int row = rowA0 + w * 32 + mi * 16 + lr + j;
#pragma unroll
      for (int ni = 0; ni < 2; ++ni) {
        const int hc = nrow0 + ni * 16 + lc;
        const int bcol = ni * 16 + lc;
        const float zi = acc[0][mi][ni][j] + biasLDS[0][bcol];
        const float zf = acc[1][mi][ni][j] + biasLDS[1][bcol];
        const float zg = acc[2][mi][ni][j] + biasLDS[2][bcol];
        const float zo = acc[3][mi][ni][j] + biasLDS[3][bcol];
        const float ig = sigmoidf_(zi);
        const float fg = sigmoidf_(zf);
        const float gg = tanhf(zg);
        const float og = sigmoidf_(zo);
        const size_t idx = (size_t)row * 512 + hc;
        const float cv = p.c[idx];
        const float cn = fg * cv + ig * gg;
        const float hn = og * tanhf(cn);
        p.outh[idx] = hn;
        p.outc[idx] = cn;
      }
    }
  }
}

extern "C" void kernel_launch(void* const* d_in, const int* in_sizes, int n_in,
                              void* d_out, int out_size, void* d_ws, size_t ws_size,
                              hipStream_t stream) {
  Params p;
  p.u = (const float*)d_in[0];
  p.h = (const float*)d_in[1];
  p.c = (const float*)d_in[2];
  p.W[0] = (const float*)d_in[3];
  p.bW[0] = (const float*)d_in[4];
  p.W[1] = (const float*)d_in[5];
  p.bW[1] = (const float*)d_in[6];
  p.W[2] = (const float*)d_in[7];
  p.bW[2] = (const float*)d_in[8];
  p.W[3] = (const float*)d_in[9];
  p.bW[3] = (const float*)d_in[10];
  p.U[0] = (const float*)d_in[11];
  p.U[1] = (const float*)d_in[12];
  p.U[2] = (const float*)d_in[13];
  p.U[3] = (const float*)d_in[14];
  p.bE[0] = (const float*)d_in[15];
  p.bE[1] = (const float*)d_in[16];
  p.bE[2] = (const float*)d_in[17];
  p.bE[3] = (const float*)d_in[18];
  p.outh = (float*)d_out;
  p.outc = (float*)d_out + (size_t)BDIM * HDIM;

  dim3 grid(2048);
  dim3 block(256);
  hipLaunchKernelGGL(lstm_cell_kernel, grid, block, 0, stream, p);
}